// Round 1
// 401.400 us; speedup vs baseline: 1.6059x; 1.6059x over previous
//
#include <hip/hip_runtime.h>
#include <hip/hip_bf16.h>
#include <stdint.h>

#define BATCH 32
#define CIN   256
#define COUT  256
#define FH    64
#define FW    64
#define NK    4
#define CTX   256
#define TEMP  30.0f

typedef __attribute__((ext_vector_type(8))) short bf16x8;
typedef __attribute__((ext_vector_type(4))) float f32x4;

__device__ __forceinline__ unsigned short f2bf(float f) {
    union { float f; uint32_t u; } a; a.f = f;
    uint32_t r = a.u + 0x7fffu + ((a.u >> 16) & 1u);
    return (unsigned short)(r >> 16);
}

// ws layout
#define WMIX_OFF  1024
#define WMIX_BYTES (32u * 9u * 8u * 4u * 256u * 16u)        // 37,748,736
#define XP_OFF    (WMIX_OFF + WMIX_BYTES)
// xp: [b][ch8][q4][y66][col68][r8] bf16  -> 32*8*4*66*68*16 B = 73,383,936

// ---------------- Kernel 1: attention ---------------------------------------
__global__ void attn_kernel(const float* __restrict__ g,
                            const float* __restrict__ dw,
                            const float* __restrict__ db,
                            float* __restrict__ att) {
    int tid = threadIdx.x;          // 128 threads: (b,k) = (tid>>2, tid&3)
    int b = tid >> 2;
    int k = tid & 3;
    float acc = db[k];
    const float* gp = g + b * CTX;
    for (int i = 0; i < CTX; ++i)
        acc += gp[i] * dw[i * NK + k];
    acc *= (1.0f / TEMP);
    float m = acc;
    m = fmaxf(m, __shfl_xor(m, 1));
    m = fmaxf(m, __shfl_xor(m, 2));
    float e = expf(acc - m);
    float s = e;
    s += __shfl_xor(s, 1);
    s += __shfl_xor(s, 2);
    att[b * NK + k] = e / s;
}

// ---------------- Kernel 2: expert mix -> wmix [b][tap][ch][q][co][r8] ------
// Rewritten: two-phase LDS transpose.
// Phase 1: coalesced float4 streams through weight's NATIVE layout
//          (contiguous (ci,tap) per (k,co)), fp32 mix of 4 experts in
//          registers, bf16 into padded LDS tile [nb2][co8][2308].
// Phase 2: strided (9-elem) gather from LDS, fully-coalesced uint4 global
//          stores in the conv-consumed layout (identical to before).
// Tile: 8 co x 2 batches per block -> grid (32 cog, 16 bg) = 512 blocks.
// LDS 73,856 B -> 2 blocks/CU. Weight tile reused for 2 batches in-reg;
// cross-block re-reads (288 KB/tile) are L2-resident.
__global__ __launch_bounds__(256, 2) void mix_kernel(
        const float* __restrict__ weight,
        const float* __restrict__ att,
        uint32_t* __restrict__ wmix) {
    __shared__ __align__(16) short S[2 * 8 * 2308];   // [nb][co8][2308], 73,856 B

    const int t   = threadIdx.x;
    const int cog = blockIdx.x;          // 0..31, 8 co each
    const int bg  = blockIdx.y;          // 0..15, 2 b each
    const int co0 = cog * 8;
    const int b0  = bg * 2;
    const size_t EST = (size_t)COUT * CIN * 9;       // floats per expert

    float a[2][4];
#pragma unroll
    for (int nb = 0; nb < 2; ++nb)
#pragma unroll
        for (int k = 0; k < 4; ++k)
            a[nb][k] = att[(b0 + nb) * 4 + k];

    // ---- phase 1: weight -> mixed bf16 in LDS ----
    const int co_l  = t >> 5;            // 0..7
    const int inner = t & 31;            // 0..31
    const float* wbase = weight + (size_t)(co0 + co_l) * 2304;

#pragma unroll 2
    for (int i = 0; i < 18; ++i) {
        const int e4 = inner + 32 * i;   // float4 index within (k,co), 0..575
        float4 w[4];
#pragma unroll
        for (int k = 0; k < 4; ++k)
            w[k] = *(const float4*)(wbase + k * EST + (size_t)e4 * 4);
#pragma unroll
        for (int nb = 0; nb < 2; ++nb) {
            float mx = a[nb][0] * w[0].x + a[nb][1] * w[1].x + a[nb][2] * w[2].x + a[nb][3] * w[3].x;
            float my = a[nb][0] * w[0].y + a[nb][1] * w[1].y + a[nb][2] * w[2].y + a[nb][3] * w[3].y;
            float mz = a[nb][0] * w[0].z + a[nb][1] * w[1].z + a[nb][2] * w[2].z + a[nb][3] * w[3].z;
            float mw = a[nb][0] * w[0].w + a[nb][1] * w[1].w + a[nb][2] * w[2].w + a[nb][3] * w[3].w;
            uint32_t lo = (uint32_t)f2bf(mx) | ((uint32_t)f2bf(my) << 16);
            uint32_t hi = (uint32_t)f2bf(mz) | ((uint32_t)f2bf(mw) << 16);
            uint2* d = (uint2*)(S + ((nb * 8 + co_l) * 2308 + e4 * 4));
            *d = make_uint2(lo, hi);
        }
    }
    __syncthreads();

    // ---- phase 2: LDS -> wmix, coalesced 16B stores ----
    const int co_w = t & 7;              // 0..7
    const int slot = t >> 3;             // 0..31
#pragma unroll 2
    for (int j = 0; j < 18; ++j) {
        const int GG  = j * 32 + slot;   // 0..575 over (b_l, tap, ch, q)
        const int b_l = (GG >= 288) ? 1 : 0;
        const int rem = GG - b_l * 288;  // tap*32 + ch*4 + q
        const int tap = rem >> 5;
        const int ch  = (rem >> 2) & 7;
        const int q   = rem & 3;
        const short* sp = S + (b_l * 8 + co_w) * 2308;
        const int ebase = (ch * 32 + q * 8) * 9 + tap;
        uint32_t d[4];
#pragma unroll
        for (int rp = 0; rp < 4; ++rp) {
            uint32_t lo = (uint16_t)sp[ebase + (2 * rp) * 9];
            uint32_t hi = (uint16_t)sp[ebase + (2 * rp + 1) * 9];
            d[rp] = lo | (hi << 16);
        }
        uint32_t* dst = wmix +
            ((((size_t)((b0 + b_l) * 9 + tap) * 8 + ch) * 4 + q) * 256 + co0 + co_w) * 4;
        *(uint4*)dst = make_uint4(d[0], d[1], d[2], d[3]);
    }
}

// ---------------- Kernel 3: x -> bf16 halo-padded xp ------------------------
// xp[b][ch][q][y66][col68][r8]; y=0/65 zero rows, col 0,65,66,67 zero.
__global__ void xpad_kernel(const float* __restrict__ x,
                            uint32_t* __restrict__ xp) {
    __shared__ uint32_t P[1088];    // [q4][col68][rpair4] dwords = 4352 B
    const int t  = threadIdx.x;
    const int y  = blockIdx.x;      // 0..65
    const int ch = blockIdx.y;      // 0..7
    const int b  = blockIdx.z;      // 0..31

    // zero LDS
    for (int i = t; i < 1088; i += 256) P[i] = 0;
    __syncthreads();

    if (y >= 1 && y <= 64) {
        const int ci_l = t >> 3;            // 0..31
        const int col0 = (t & 7) * 8;       // 0..56
        const float* xr = x + (((size_t)(b * 256 + ch * 32 + ci_l) * 64) + (y - 1)) * 64 + col0;
        float4 v0 = *(const float4*)xr;
        float4 v1 = *(const float4*)(xr + 4);
        unsigned short bf[8];
        bf[0] = f2bf(v0.x); bf[1] = f2bf(v0.y); bf[2] = f2bf(v0.z); bf[3] = f2bf(v0.w);
        bf[4] = f2bf(v1.x); bf[5] = f2bf(v1.y); bf[6] = f2bf(v1.z); bf[7] = f2bf(v1.w);
        const int q = ci_l >> 3, r = ci_l & 7;
        unsigned short* Ps = (unsigned short*)P;
#pragma unroll
        for (int j = 0; j < 8; ++j)
            Ps[(q * 68 + (col0 + j + 1)) * 8 + r] = bf[j];
    }
    __syncthreads();

    // write out: per q plane, 272 dwords, planes 71808 B apart
    const int q = t >> 6, l = t & 63;
    uint32_t* base = xp + (((((size_t)(b * 8 + ch) * 4 + q) * 66) + y) * 68) * 4;  // dwords
#pragma unroll
    for (int i = 0; i < 4; ++i)
        base[l + i * 64] = P[q * 272 + l + i * 64];
    if (l < 16) base[l + 256] = P[q * 272 + l + 256];
}

// ---------------- Kernel 4: implicit-GEMM conv, m97-style -------------------
// Block 256 thr (4 waves, 2co x 2px). Tile 128co x 128px (rows y0,y0+1).
// Wave: 64co x 64px = 4x4 of mfma_f32_16x16x32_bf16.
// Phase = (ci-chunk of 32) x (dy group of 3 taps): stage A3 24.6KB + B2 8.7KB
// entirely via global_load_lds(16B), then 3 dx K-steps of 16 MFMAs.
__global__ __launch_bounds__(256, 3) void conv_mfma(
        const char* __restrict__ xp,
        const char* __restrict__ wmix,
        float* __restrict__ out) {
    __shared__ __align__(16) short As[3 * 4 * 128 * 8];   // 24576 B [dx][q][co128][r8]
    __shared__ __align__(16) short Bs[4 * 2 * 68 * 8];    //  8704 B [q][row2][col68][r8]

    const int tid  = threadIdx.x;
    const int lane = tid & 63;
    const int wv   = tid >> 6;
    const int wm   = wv & 1;          // co half
    const int wn   = wv >> 1;         // px half == image row offset
    const int l4   = lane >> 4;       // k-quad
    const int m16  = lane & 15;

    const int ptile = blockIdx.x;     // 0..31
    const int coT   = blockIdx.y;     // 0..1
    const int b     = blockIdx.z;     // 0..31
    const int y0    = ptile * 2;

    const char* wmix_b = wmix + (size_t)b * 9 * 8 * 4 * 256 * 16;
    const char* xp_b   = xp + (size_t)b * 8 * 4 * 66 * 68 * 16;

    f32x4 acc[4][4];
#pragma unroll
    for (int i = 0; i < 4; ++i)
#pragma unroll
        for (int j = 0; j < 4; ++j)
            acc[i][j] = (f32x4){0.f, 0.f, 0.f, 0.f};

    const int aLane = l4 * 2048 + wm * 1024 + m16 * 16;   // byte off in As
    const int bLane = l4 * 2176 + wn * 1088 + m16 * 16;   // byte off in Bs

#pragma unroll 1
    for (int ch = 0; ch < 8; ++ch) {
#pragma unroll 1
        for (int dy = 0; dy < 3; ++dy) {
            __syncthreads();   // previous phase reads done
            // ---- A staging: 24 segments of 1KB (6 per wave) ----
#pragma unroll
            for (int i = 0; i < 6; ++i) {
                const int s  = wv + i * 4;      // 0..23
                const int dx = s >> 3;
                const int q  = (s >> 1) & 3;
                const int h  = s & 1;
                const char* gsrc = wmix_b
                    + ((size_t)((dy * 3 + dx) * 8 + ch) * 4 + q) * 4096
                    + (coT * 128 + h * 64 + lane) * 16;
                char* ldst = (char*)As + ((dx * 4 + q) * 128 + h * 64 + lane) * 16;
                __builtin_amdgcn_global_load_lds(
                    (const __attribute__((address_space(1))) void*)gsrc,
                    (__attribute__((address_space(3))) void*)ldst, 16, 0, 0);
            }
            // ---- B staging: wave wv stages q=wv, rows yb..yb+1 (2176 B) ----
            {
                const int yb = y0 + dy;     // padded-row index, 0..64
                const char* gsrc = xp_b
                    + (((size_t)ch * 4 + wv) * 66 + yb) * 1088 + lane * 16;
                char* ldst = (char*)Bs + wv * 2176 + lane * 16;
                __builtin_amdgcn_global_load_lds(
                    (const __attribute__((address_space(1))) void*)gsrc,
                    (__attribute__((address_space(3))) void*)ldst, 16, 0, 0);
                __builtin_amdgcn_global_load_lds(
                    (const __attribute__((address_space(1))) void*)(gsrc + 1024),
                    (__attribute__((address_space(3))) void*)(ldst + 1024), 16, 0, 0);
                if (lane < 8)
                    __builtin_amdgcn_global_load_lds(
                        (const __attribute__((address_space(1))) void*)(gsrc + 2048),
                        (__attribute__((address_space(3))) void*)(ldst + 2048), 16, 0, 0);
            }
            __syncthreads();   // staging visible

            // ---- compute: 3 dx K-steps x 16 MFMAs ----
#pragma unroll
            for (int dx = 0; dx < 3; ++dx) {
                bf16x8 a[4], bb[4];
#pragma unroll
                for (int sm = 0; sm < 4; ++sm)
                    a[sm] = *(const bf16x8*)((const char*)As + dx * 8192 + aLane + sm * 256);
#pragma unroll
                for (int sn = 0; sn < 4; ++sn)
                    bb[sn] = *(const bf16x8*)((const char*)Bs + bLane + dx * 16 + sn * 256);
#pragma unroll
                for (int sm = 0; sm < 4; ++sm)
#pragma unroll
                    for (int sn = 0; sn < 4; ++sn)
                        acc[sm][sn] = __builtin_amdgcn_mfma_f32_16x16x32_bf16(
                            a[sm], bb[sn], acc[sm][sn], 0, 0, 0);
            }
        }
    }

    // ---- epilogue: D col=lane&15 (px), row=(lane>>4)*4+reg (co) ----
    const int y = y0 + wn;
#pragma unroll
    for (int sm = 0; sm < 4; ++sm) {
#pragma unroll
        for (int sn = 0; sn < 4; ++sn) {
#pragma unroll
            for (int r = 0; r < 4; ++r) {
                const int co = coT * 128 + wm * 64 + sm * 16 + l4 * 4 + r;
                const int xx = sn * 16 + m16;
                out[(((size_t)b * COUT + co) * FH + y) * FW + xx] = acc[sm][sn][r];
            }
        }
    }
}

extern "C" void kernel_launch(void* const* d_in, const int* in_sizes, int n_in,
                              void* d_out, int out_size, void* d_ws, size_t ws_size,
                              hipStream_t stream) {
    const float* x       = (const float*)d_in[0];
    const float* g       = (const float*)d_in[1];
    const float* weight  = (const float*)d_in[2];
    const float* dense_w = (const float*)d_in[3];
    const float* dense_b = (const float*)d_in[4];
    float* out = (float*)d_out;

    float*    att  = (float*)d_ws;
    uint32_t* wmix = (uint32_t*)((char*)d_ws + WMIX_OFF);
    uint32_t* xp   = (uint32_t*)((char*)d_ws + XP_OFF);

    attn_kernel<<<1, 128, 0, stream>>>(g, dense_w, dense_b, att);
    mix_kernel<<<dim3(32, 16), 256, 0, stream>>>(weight, att, wmix);
    xpad_kernel<<<dim3(66, 8, BATCH), 256, 0, stream>>>(x, xp);

    dim3 grid(32, 2, BATCH);
    conv_mfma<<<grid, 256, 0, stream>>>((const char*)xp, (const char*)wmix, out);
}